// Round 3
// baseline (310.375 us; speedup 1.0000x reference)
//
#include <hip/hip_runtime.h>

// d_ws layout: ws[0] = running sum of (bg partial + fg partial), float32.

__global__ void _pcl_init_ws(float* __restrict__ ws) {
    if (threadIdx.x == 0 && blockIdx.x == 0) ws[0] = 0.0f;
}

__global__ void _pcl_loss_reduce(const float* __restrict__ pcl_prob,   // [n, c]
                                 const int*   __restrict__ labels,     // [n]
                                 const float* __restrict__ clw,        // [n]
                                 const int*   __restrict__ pc_labels,  // [g]
                                 const float* __restrict__ pc_probs,   // [g]
                                 const float* __restrict__ iclw,       // [g]
                                 const float* __restrict__ im_labels,  // [c]
                                 float* __restrict__ acc,
                                 int n, int g, int c) {
    const int total = n + g;
    const float im0 = im_labels[0];
    float local = 0.0f;

    for (int i = blockIdx.x * blockDim.x + threadIdx.x; i < total;
         i += gridDim.x * blockDim.x) {
        if (i < n) {
            // background term: labels[i]==0 && im_labels[0]!=0
            if (labels[i] == 0 && im0 != 0.0f) {
                // strided column-0 load gated behind the mask so exec-masked
                // lanes don't fetch their cache line
                float p = pcl_prob[(size_t)i * (size_t)c];
                local += clw[i] * logf(p);
            }
        } else {
            int gi = i - n;
            int lab = pc_labels[gi];
            if (lab > 0 && im_labels[lab] != 0.0f) {
                local += iclw[gi] * logf(pc_probs[gi]);
            }
        }
    }

    // wave-64 butterfly reduce
    #pragma unroll
    for (int off = 32; off > 0; off >>= 1)
        local += __shfl_down(local, off, 64);

    if ((threadIdx.x & 63) == 0)
        atomicAdd(acc, local);
}

__global__ void _pcl_finalize(const float* __restrict__ acc,
                              float* __restrict__ out, float inv_n) {
    if (threadIdx.x == 0 && blockIdx.x == 0)
        out[0] = -acc[0] * inv_n;
}

extern "C" void kernel_launch(void* const* d_in, const int* in_sizes, int n_in,
                              void* d_out, int out_size, void* d_ws, size_t ws_size,
                              hipStream_t stream) {
    const float* pcl_prob  = (const float*)d_in[0];
    const int*   labels    = (const int*)  d_in[1];
    const float* clw       = (const float*)d_in[2];
    // d_in[3] gt_assignment — unused by the loss
    const int*   pc_labels = (const int*)  d_in[4];
    const float* pc_probs  = (const float*)d_in[5];
    // d_in[6] pc_count — unused by the loss
    const float* iclw      = (const float*)d_in[7];
    const float* im_labels = (const float*)d_in[8];

    const int n = in_sizes[1];   // N (labels)
    const int g = in_sizes[4];   // G (pc_labels)
    const int c = in_sizes[8];   // C (im_labels_real)

    float* acc = (float*)d_ws;
    float* out = (float*)d_out;

    _pcl_init_ws<<<1, 1, 0, stream>>>(acc);

    const int total = n + g;
    const int block = 256;
    int grid = (total + block - 1) / block;
    if (grid > 2048) grid = 2048;
    _pcl_loss_reduce<<<grid, block, 0, stream>>>(
        pcl_prob, labels, clw, pc_labels, pc_probs, iclw, im_labels,
        acc, n, g, c);

    _pcl_finalize<<<1, 1, 0, stream>>>(acc, out, 1.0f / (float)n);
}

// Round 4
// 213.602 us; speedup vs baseline: 1.4531x; 1.4531x over previous
//
#include <hip/hip_runtime.h>

// d_ws layout: ws[0..grid-1] = per-block partial sums (float32), written
// unconditionally by every block each launch (ws is re-poisoned 0xAA).

__global__ void _pcl_loss_reduce(const float* __restrict__ pcl_prob,   // [n, c]
                                 const int*   __restrict__ labels,     // [n]
                                 const float* __restrict__ clw,        // [n]
                                 const int*   __restrict__ pc_labels,  // [g]
                                 const float* __restrict__ pc_probs,   // [g]
                                 const float* __restrict__ iclw,       // [g]
                                 const float* __restrict__ im_labels,  // [c]
                                 float* __restrict__ partials,
                                 int n, int g, int c) {
    const int total = n + g;
    const float im0 = im_labels[0];
    float local = 0.0f;

    for (int i = blockIdx.x * blockDim.x + threadIdx.x; i < total;
         i += gridDim.x * blockDim.x) {
        if (i < n) {
            // background term: labels[i]==0 && im_labels[0]!=0
            if (labels[i] == 0 && im0 != 0.0f) {
                // strided column-0 load gated behind the mask so exec-masked
                // lanes don't fetch their cache line
                float p = pcl_prob[(size_t)i * (size_t)c];
                local += clw[i] * logf(p);
            }
        } else {
            int gi = i - n;
            int lab = pc_labels[gi];
            if (lab > 0 && im_labels[lab] != 0.0f) {
                local += iclw[gi] * logf(pc_probs[gi]);
            }
        }
    }

    // wave-64 butterfly reduce
    #pragma unroll
    for (int off = 32; off > 0; off >>= 1)
        local += __shfl_down(local, off, 64);

    // cross-wave reduce via LDS, then ONE plain store per block (no atomics:
    // 8192 same-address atomicAdds were the 108 us bottleneck in round 3 —
    // duration was identical on L3-hit replays, i.e. pure RMW serialization)
    __shared__ float sm[4];
    const int wid = threadIdx.x >> 6;
    if ((threadIdx.x & 63) == 0) sm[wid] = local;
    __syncthreads();
    if (threadIdx.x == 0)
        partials[blockIdx.x] = sm[0] + sm[1] + sm[2] + sm[3];
}

__global__ void _pcl_finalize(const float* __restrict__ partials, int nparts,
                              float* __restrict__ out, float inv_n) {
    float local = 0.0f;
    for (int i = threadIdx.x; i < nparts; i += blockDim.x)
        local += partials[i];

    #pragma unroll
    for (int off = 32; off > 0; off >>= 1)
        local += __shfl_down(local, off, 64);

    __shared__ float sm[4];
    const int wid = threadIdx.x >> 6;
    if ((threadIdx.x & 63) == 0) sm[wid] = local;
    __syncthreads();
    if (threadIdx.x == 0)
        out[0] = -(sm[0] + sm[1] + sm[2] + sm[3]) * inv_n;
}

extern "C" void kernel_launch(void* const* d_in, const int* in_sizes, int n_in,
                              void* d_out, int out_size, void* d_ws, size_t ws_size,
                              hipStream_t stream) {
    const float* pcl_prob  = (const float*)d_in[0];
    const int*   labels    = (const int*)  d_in[1];
    const float* clw       = (const float*)d_in[2];
    // d_in[3] gt_assignment — unused by the loss
    const int*   pc_labels = (const int*)  d_in[4];
    const float* pc_probs  = (const float*)d_in[5];
    // d_in[6] pc_count — unused by the loss
    const float* iclw      = (const float*)d_in[7];
    const float* im_labels = (const float*)d_in[8];

    const int n = in_sizes[1];   // N (labels)
    const int g = in_sizes[4];   // G (pc_labels)
    const int c = in_sizes[8];   // C (im_labels_real)

    float* partials = (float*)d_ws;
    float* out = (float*)d_out;

    const int total = n + g;
    const int block = 256;
    int grid = (total + block - 1) / block;
    if (grid > 2048) grid = 2048;

    _pcl_loss_reduce<<<grid, block, 0, stream>>>(
        pcl_prob, labels, clw, pc_labels, pc_probs, iclw, im_labels,
        partials, n, g, c);

    _pcl_finalize<<<1, block, 0, stream>>>(partials, grid, out, 1.0f / (float)n);
}

// Round 12
// 211.235 us; speedup vs baseline: 1.4693x; 1.0112x over previous
//
#include <hip/hip_runtime.h>

// d_ws layout: ws[0..grid-1] = per-block partial sums (float32), written
// unconditionally by every block each launch (ws is re-poisoned 0xAA).
//
// Round-3→4 lesson: 8192 same-address atomicAdds cost ~94 us (cross-XCD RMW
// serialization); per-block plain stores + single-block finalize fixed it.
// Round 5: 4 proposals/thread (int4 labels, float4 clw) for MLP depth —
// the 4 gated pcl_prob[:,0] line-fetches per thread are independent.

__global__ void _pcl_loss_reduce(const float* __restrict__ pcl_prob,   // [n, c]
                                 const int*   __restrict__ labels,     // [n]
                                 const float* __restrict__ clw,        // [n]
                                 const int*   __restrict__ pc_labels,  // [g]
                                 const float* __restrict__ pc_probs,   // [g]
                                 const float* __restrict__ iclw,       // [g]
                                 const float* __restrict__ im_labels,  // [c]
                                 float* __restrict__ partials,
                                 int n, int g, int c) {
    const int nv = (n + 3) >> 2;      // number of 4-wide proposal groups
    const int total = nv + g;
    const float im0 = im_labels[0];
    float local = 0.0f;

    for (int i = blockIdx.x * blockDim.x + threadIdx.x; i < total;
         i += gridDim.x * blockDim.x) {
        if (i < nv) {
            const int base = i << 2;
            if (base + 3 < n) {
                // vector path: one int4 + one float4 coalesced load, then up
                // to 4 independent gated column-0 line fetches
                const int4   lab4 = *reinterpret_cast<const int4*>(labels + base);
                const float4 w4   = *reinterpret_cast<const float4*>(clw + base);
                if (im0 != 0.0f) {
                    if (lab4.x == 0)
                        local += w4.x * logf(pcl_prob[(size_t)(base + 0) * (size_t)c]);
                    if (lab4.y == 0)
                        local += w4.y * logf(pcl_prob[(size_t)(base + 1) * (size_t)c]);
                    if (lab4.z == 0)
                        local += w4.z * logf(pcl_prob[(size_t)(base + 2) * (size_t)c]);
                    if (lab4.w == 0)
                        local += w4.w * logf(pcl_prob[(size_t)(base + 3) * (size_t)c]);
                }
            } else {
                for (int k = base; k < n; ++k) {
                    if (labels[k] == 0 && im0 != 0.0f)
                        local += clw[k] * logf(pcl_prob[(size_t)k * (size_t)c]);
                }
            }
        } else {
            const int gi = i - nv;
            const int lab = pc_labels[gi];
            if (lab > 0 && im_labels[lab] != 0.0f)
                local += iclw[gi] * logf(pc_probs[gi]);
        }
    }

    // wave-64 butterfly reduce
    #pragma unroll
    for (int off = 32; off > 0; off >>= 1)
        local += __shfl_down(local, off, 64);

    __shared__ float sm[4];
    const int wid = threadIdx.x >> 6;
    if ((threadIdx.x & 63) == 0) sm[wid] = local;
    __syncthreads();
    if (threadIdx.x == 0)
        partials[blockIdx.x] = sm[0] + sm[1] + sm[2] + sm[3];
}

__global__ void _pcl_finalize(const float* __restrict__ partials, int nparts,
                              float* __restrict__ out, float inv_n) {
    float local = 0.0f;
    for (int i = threadIdx.x; i < nparts; i += blockDim.x)
        local += partials[i];

    #pragma unroll
    for (int off = 32; off > 0; off >>= 1)
        local += __shfl_down(local, off, 64);

    __shared__ float sm[4];
    const int wid = threadIdx.x >> 6;
    if ((threadIdx.x & 63) == 0) sm[wid] = local;
    __syncthreads();
    if (threadIdx.x == 0)
        out[0] = -(sm[0] + sm[1] + sm[2] + sm[3]) * inv_n;
}

extern "C" void kernel_launch(void* const* d_in, const int* in_sizes, int n_in,
                              void* d_out, int out_size, void* d_ws, size_t ws_size,
                              hipStream_t stream) {
    const float* pcl_prob  = (const float*)d_in[0];
    const int*   labels    = (const int*)  d_in[1];
    const float* clw       = (const float*)d_in[2];
    // d_in[3] gt_assignment — unused by the loss
    const int*   pc_labels = (const int*)  d_in[4];
    const float* pc_probs  = (const float*)d_in[5];
    // d_in[6] pc_count — unused by the loss
    const float* iclw      = (const float*)d_in[7];
    const float* im_labels = (const float*)d_in[8];

    const int n = in_sizes[1];   // N (labels)
    const int g = in_sizes[4];   // G (pc_labels)
    const int c = in_sizes[8];   // C (im_labels_real)

    float* partials = (float*)d_ws;
    float* out = (float*)d_out;

    const int nv = (n + 3) >> 2;
    const int total = nv + g;
    const int block = 256;
    int grid = (total + block - 1) / block;
    if (grid > 2048) grid = 2048;

    _pcl_loss_reduce<<<grid, block, 0, stream>>>(
        pcl_prob, labels, clw, pc_labels, pc_probs, iclw, im_labels,
        partials, n, g, c);

    _pcl_finalize<<<1, block, 0, stream>>>(partials, grid, out, 1.0f / (float)n);
}